// Round 14
// baseline (492.019 us; speedup 1.0000x reference)
//
#include <hip/hip_runtime.h>

using bf16x8 = __attribute__((ext_vector_type(8))) short;
using short8 = __attribute__((ext_vector_type(8))) short;
using s16x4  = __attribute__((ext_vector_type(4))) short;
using f32x4  = __attribute__((ext_vector_type(4))) float;
using u32x4  = __attribute__((ext_vector_type(4))) unsigned;
using ull    = unsigned long long;

#define T_SEQ 512
#define MFMA(A, B, C) __builtin_amdgcn_mfma_f32_16x16x32_bf16((A), (B), (C), 0, 0, 0)

// Raw barrier: lgkmcnt(0) makes this wave's ds_write visible; no vmcnt drain.
#define BARRIER()                                            \
    do {                                                     \
        __builtin_amdgcn_sched_barrier(0);                   \
        asm volatile("s_waitcnt lgkmcnt(0)" ::: "memory");   \
        __builtin_amdgcn_s_barrier();                        \
        __builtin_amdgcn_sched_barrier(0);                   \
    } while (0)

static constexpr float NL2E  = -1.44269504f;   // -log2(e)
static constexpr float N2L2E = -2.88539008f;   // -2*log2(e)

// Truncation split: hi = bf16-truncate(v), lo = bf16-truncate(v - hi) (exact residual).
__device__ __forceinline__ void split8_tr(f32x4 a, f32x4 b, bf16x8& hi, bf16x8& lo) {
    u32x4 ua = __builtin_bit_cast(u32x4, a);
    u32x4 ub = __builtin_bit_cast(u32x4, b);
    u32x4 m  = {0xffff0000u, 0xffff0000u, 0xffff0000u, 0xffff0000u};
    f32x4 ra = a - __builtin_bit_cast(f32x4, ua & m);
    f32x4 rb = b - __builtin_bit_cast(f32x4, ub & m);
    short8 sa  = __builtin_bit_cast(short8, a);
    short8 sb  = __builtin_bit_cast(short8, b);
    short8 sra = __builtin_bit_cast(short8, ra);
    short8 srb = __builtin_bit_cast(short8, rb);
    hi = __builtin_shufflevector(sa, sb, 1, 3, 5, 7, 9, 11, 13, 15);
    lo = __builtin_shufflevector(sra, srb, 1, 3, 5, 7, 9, 11, 13, 15);
}

__device__ __forceinline__ void split4_tr(f32x4 a, s16x4& hi, s16x4& lo) {
    u32x4 ua = __builtin_bit_cast(u32x4, a);
    u32x4 m  = {0xffff0000u, 0xffff0000u, 0xffff0000u, 0xffff0000u};
    f32x4 ra = a - __builtin_bit_cast(f32x4, ua & m);
    short8 sa  = __builtin_bit_cast(short8, a);
    short8 sra = __builtin_bit_cast(short8, ra);
    hi = __builtin_shufflevector(sa, sa, 1, 3, 5, 7);
    lo = __builtin_shufflevector(sra, sra, 1, 3, 5, 7);
}

__device__ __forceinline__ bf16x8 combine8(ull lo8, ull hi8) {
    u32x4 v = {(unsigned)lo8, (unsigned)(lo8 >> 32),
               (unsigned)hi8, (unsigned)(hi8 >> 32)};
    return __builtin_bit_cast(bf16x8, v);
}
__device__ __forceinline__ bf16x8 combine8_sel(ull own, ull other, int m) {
    return combine8(m ? other : own, m ? own : other);
}

// 9-MFMA product block: 3 independent acc chains (hiW*hi, hiW*lo, loW*hi).
__device__ __forceinline__ void mfma9(const bf16x8 (&WH)[3], const bf16x8 (&WL)[3],
                                      bf16x8 inh, bf16x8 inl,
                                      f32x4 c0, f32x4 c1, f32x4 c2,
                                      f32x4& a0, f32x4& a1, f32x4& a2) {
    a0 = MFMA(WH[0], inh, c0); a1 = MFMA(WH[1], inh, c1); a2 = MFMA(WH[2], inh, c2);
    a0 = MFMA(WH[0], inl, a0); a1 = MFMA(WH[1], inl, a1); a2 = MFMA(WH[2], inl, a2);
    a0 = MFMA(WL[0], inh, a0); a1 = MFMA(WL[1], inh, a1); a2 = MFMA(WL[2], inh, a2);
}

// Gates for TWO groups' 4 hidden units each, level-major across all 8 element
// chains so both groups' transcendental latencies overlap.
__device__ __forceinline__ void gate4x2(const f32x4 (&aR)[2], const f32x4 (&aZ)[2],
                                        const f32x4 (&iN)[2], const f32x4 (&sN)[2],
                                        float (&hf)[2][4]) {
    float er[2][4], ez[2][4];
    #pragma unroll
    for (int g = 0; g < 2; ++g)
        #pragma unroll
        for (int j = 0; j < 4; ++j) er[g][j] = __builtin_amdgcn_exp2f(aR[g][j] * NL2E);
    #pragma unroll
    for (int g = 0; g < 2; ++g)
        #pragma unroll
        for (int j = 0; j < 4; ++j) ez[g][j] = __builtin_amdgcn_exp2f(aZ[g][j] * NL2E);
    float gr[2][4], gz[2][4];
    #pragma unroll
    for (int g = 0; g < 2; ++g)
        #pragma unroll
        for (int j = 0; j < 4; ++j) gr[g][j] = __builtin_amdgcn_rcpf(1.f + er[g][j]);
    #pragma unroll
    for (int g = 0; g < 2; ++g)
        #pragma unroll
        for (int j = 0; j < 4; ++j) gz[g][j] = __builtin_amdgcn_rcpf(1.f + ez[g][j]);
    float en[2][4];
    #pragma unroll
    for (int g = 0; g < 2; ++g)
        #pragma unroll
        for (int j = 0; j < 4; ++j) {
            float u = fmaf(gr[g][j], sN[g][j], iN[g][j]);
            en[g][j] = __builtin_amdgcn_exp2f(fminf(u * N2L2E, 126.f));
        }
    float qn[2][4];
    #pragma unroll
    for (int g = 0; g < 2; ++g)
        #pragma unroll
        for (int j = 0; j < 4; ++j) qn[g][j] = __builtin_amdgcn_rcpf(1.f + en[g][j]);
    #pragma unroll
    for (int g = 0; g < 2; ++g)
        #pragma unroll
        for (int j = 0; j < 4; ++j) {
            float nn = fmaf(en[g][j] * qn[g][j], -2.f, 1.f);
            hf[g][j] = fmaf(gz[g][j], hf[g][j] - nn, nn);
        }
}

// Block = 256 threads = 4 waves = (layer L, half m), each wave processing TWO
// independent batch-groups (G=2, 32 batches/block, 128 blocks). The per-step
// serial chain (~1700cyc across R9-R13, invariant to all micro-fixes) is
// FILLED, not shrunk: group B's instructions issue inside group A's stall
// cycles (two interleaved recurrences per wave). Latency-bound, so idle CUs
// (128 of 256) are irrelevant.
// Frag map: batch = gbase+(lane&15), q=lane>>4; elems 0..3 = units 4q+j,
// 4..7 = 16+4q+j (same map A and B). D: col=lane&15, row=4q+reg (m89).
__global__ __launch_bounds__(256, 1)
void gru2_quad2(const float* __restrict__ x,
                const float* __restrict__ W_ih0, const float* __restrict__ W_hh0,
                const float* __restrict__ b_ih0, const float* __restrict__ b_hh0,
                const float* __restrict__ W_ih1, const float* __restrict__ W_hh1,
                const float* __restrict__ b_ih1, const float* __restrict__ b_hh1,
                const float* __restrict__ W_proj, const float* __restrict__ b_proj,
                float* __restrict__ out)
{
    const int tid  = threadIdx.x;
    const int wid  = tid >> 6;
    const int L    = wid >> 1;        // 0: layer0, 1: layer1
    const int m    = wid & 1;         // row half
    const int lane = tid & 63;
    const int r16  = lane & 15;
    const int q    = lane >> 4;
    const int b0   = blockIdx.x * 32; // 2 groups of 16 batches

    // [group][half][layer][parity][lane] (8B each) -> 4KB + 4KB
    __shared__ ull pubH_[2][2][2][2][64];
    __shared__ ull pubL_[2][2][2][2][64];

    const float* Wx = L ? W_ih1 : W_ih0;
    const float* Wh = L ? W_hh1 : W_hh0;
    const float* bx = L ? b_ih1 : b_ih0;
    const float* bh = L ? b_hh1 : b_hh0;

    // weight fragments for tiles {m, 2+m, 4+m}; g: 0=r, 1=z, 2=n (shared by groups)
    bf16x8 WxH[3], WxL[3], WhH[3], WhL[3];
    f32x4 bxf[3], bhf[3];
    #pragma unroll
    for (int g = 0; g < 3; ++g) {
        const int tile = 2 * g + m;
        const float* p1 = Wx + (16 * tile + r16) * 32 + 4 * q;
        split8_tr(*(const f32x4*)p1, *(const f32x4*)(p1 + 16), WxH[g], WxL[g]);
        const float* p2 = Wh + (16 * tile + r16) * 32 + 4 * q;
        split8_tr(*(const f32x4*)p2, *(const f32x4*)(p2 + 16), WhH[g], WhL[g]);
        bxf[g] = *(const f32x4*)(bx + 16 * tile + 4 * q);
        bhf[g] = *(const f32x4*)(bh + 16 * tile + 4 * q);
    }

    float hf[2][4] = {{0.f, 0.f, 0.f, 0.f}, {0.f, 0.f, 0.f, 0.f}};
    ull ownH[2] = {0, 0}, ownL[2] = {0, 0};
    const float* xp[2];
    #pragma unroll
    for (int g = 0; g < 2; ++g)
        xp[g] = x + (size_t)(b0 + 16 * g + r16) * (T_SEQ * 32) + 4 * q;
    f32x4 xA[2] = {}, xB[2] = {};
    bf16x8 xh_cur[2] = {}, xl_cur[2] = {};

    if (L == 0) {
        // prologue: h0[0] for both groups (state = 0 -> state accs = b_hh)
        f32x4 iR[2], iZ[2], iN[2];
        #pragma unroll
        for (int g = 0; g < 2; ++g) {
            f32x4 a0 = *(const f32x4*)(xp[g]);
            f32x4 b0v = *(const f32x4*)(xp[g] + 16);
            xA[g] = *(const f32x4*)(xp[g] + 32);       // x[1] in flight
            xB[g] = *(const f32x4*)(xp[g] + 48);
            split8_tr(a0, b0v, xh_cur[g], xl_cur[g]);  // x[0]
        }
        #pragma unroll
        for (int g = 0; g < 2; ++g)
            mfma9(WxH, WxL, xh_cur[g], xl_cur[g], bxf[0], bxf[1], bxf[2],
                  iR[g], iZ[g], iN[g]);
        f32x4 aR[2], aZ[2], sN0[2];
        #pragma unroll
        for (int g = 0; g < 2; ++g) {
            aR[g] = iR[g] + bhf[0];
            aZ[g] = iZ[g] + bhf[1];
            sN0[g] = bhf[2];
        }
        gate4x2(aR, aZ, iN, sN0, hf);
        #pragma unroll
        for (int g = 0; g < 2; ++g) {
            s16x4 hi4, lo4;
            split4_tr(f32x4{hf[g][0], hf[g][1], hf[g][2], hf[g][3]}, hi4, lo4);
            ownH[g] = __builtin_bit_cast(ull, hi4);
            ownL[g] = __builtin_bit_cast(ull, lo4);
            pubH_[g][m][0][0][lane] = ownH[g];         // publish h0[0]
            pubL_[g][m][0][0][lane] = ownL[g];
            split8_tr(xA[g], xB[g], xh_cur[g], xl_cur[g]);  // x[1] -> cur
            xA[g] = *(const f32x4*)(xp[g] + 64);       // x[2] in flight
            xB[g] = *(const f32x4*)(xp[g] + 80);
        }
    } else {
        // zero h1's initial state slots (read at t=1 as parity 1)
        #pragma unroll
        for (int g = 0; g < 2; ++g) {
            pubH_[g][m][1][1][lane] = 0;
            pubL_[g][m][1][1][lane] = 0;
        }
    }

    // ---- main loop: both groups' steps interleaved inside one barrier interval ----
    #pragma unroll 1
    for (int t = 1; t < T_SEQ; ++t) {
        BARRIER();                       // prev-iter LDS pubs visible; no vmcnt drain
        const int pPrev = (t - 1) & 1;
        const int pCur  = t & 1;
        f32x4 iR[2], iZ[2], iN[2], sR[2], sZ[2], sN[2];
        if (L == 0) {
            ull oH[2], oL[2];
            #pragma unroll
            for (int g = 0; g < 2; ++g) {            // all reads first
                oH[g] = pubH_[g][1 - m][0][pPrev][lane];
                oL[g] = pubL_[g][1 - m][0][pPrev][lane];
            }
            #pragma unroll
            for (int g = 0; g < 2; ++g)              // input MFMAs: regs only
                mfma9(WxH, WxL, xh_cur[g], xl_cur[g], bxf[0], bxf[1], bxf[2],
                      iR[g], iZ[g], iN[g]);
            #pragma unroll
            for (int g = 0; g < 2; ++g) {            // state MFMAs
                bf16x8 Sh = combine8_sel(ownH[g], oH[g], m);
                bf16x8 Sl = combine8_sel(ownL[g], oL[g], m);
                mfma9(WhH, WhL, Sh, Sl, bhf[0], bhf[1], bhf[2],
                      sR[g], sZ[g], sN[g]);
            }
            #pragma unroll
            for (int g = 0; g < 2; ++g) {            // x re-split + prefetch (filler)
                split8_tr(xA[g], xB[g], xh_cur[g], xl_cur[g]);   // x[t+1]
                const int tn = (t + 2 < T_SEQ) ? t + 2 : T_SEQ - 1;
                xA[g] = *(const f32x4*)(xp[g] + (size_t)tn * 32);
                xB[g] = *(const f32x4*)(xp[g] + (size_t)tn * 32 + 16);
            }
        } else {
            ull i0H[2], i1H[2], i0L[2], i1L[2], oH[2], oL[2];
            #pragma unroll
            for (int g = 0; g < 2; ++g) {            // all reads first
                i0H[g] = pubH_[g][0][0][pPrev][lane];
                i1H[g] = pubH_[g][1][0][pPrev][lane];
                i0L[g] = pubL_[g][0][0][pPrev][lane];
                i1L[g] = pubL_[g][1][0][pPrev][lane];
                oH[g]  = pubH_[g][1 - m][1][pCur][lane];
                oL[g]  = pubL_[g][1 - m][1][pCur][lane];
            }
            #pragma unroll
            for (int g = 0; g < 2; ++g) {
                bf16x8 inh = combine8(i0H[g], i1H[g]);
                bf16x8 inl = combine8(i0L[g], i1L[g]);
                mfma9(WxH, WxL, inh, inl, bxf[0], bxf[1], bxf[2],
                      iR[g], iZ[g], iN[g]);
            }
            #pragma unroll
            for (int g = 0; g < 2; ++g) {
                bf16x8 Sh = combine8_sel(ownH[g], oH[g], m);
                bf16x8 Sl = combine8_sel(ownL[g], oL[g], m);
                mfma9(WhH, WhL, Sh, Sl, bhf[0], bhf[1], bhf[2],
                      sR[g], sZ[g], sN[g]);
            }
        }

        f32x4 aR[2], aZ[2];
        #pragma unroll
        for (int g = 0; g < 2; ++g) {
            aR[g] = sR[g] + iR[g];
            aZ[g] = sZ[g] + iZ[g];
        }
        gate4x2(aR, aZ, iN, sN, hf);

        const int pW = (L == 0) ? pCur : pPrev;      // L0 writes h_t, L1 h_{t-1}
        #pragma unroll
        for (int g = 0; g < 2; ++g) {
            s16x4 hi4, lo4;
            split4_tr(f32x4{hf[g][0], hf[g][1], hf[g][2], hf[g][3]}, hi4, lo4);
            ownH[g] = __builtin_bit_cast(ull, hi4);
            ownL[g] = __builtin_bit_cast(ull, lo4);
            pubH_[g][m][L][pW][lane] = ownH[g];
            pubL_[g][m][L][pW][lane] = ownL[g];
        }
    }

    __syncthreads();                     // h0[511] (p1), h1[510] (p0) visible
    if (L == 1) {
        // final step: h1[511] from h0[511] and h1[510], both groups
        f32x4 iR[2], iZ[2], iN[2], sR[2], sZ[2], sN[2];
        #pragma unroll
        for (int g = 0; g < 2; ++g) {
            bf16x8 inh = combine8(pubH_[g][0][0][1][lane], pubH_[g][1][0][1][lane]);
            bf16x8 inl = combine8(pubL_[g][0][0][1][lane], pubL_[g][1][0][1][lane]);
            mfma9(WxH, WxL, inh, inl, bxf[0], bxf[1], bxf[2], iR[g], iZ[g], iN[g]);
            bf16x8 Sh = combine8_sel(ownH[g], pubH_[g][1 - m][1][0][lane], m);
            bf16x8 Sl = combine8_sel(ownL[g], pubL_[g][1 - m][1][0][lane], m);
            mfma9(WhH, WhL, Sh, Sl, bhf[0], bhf[1], bhf[2], sR[g], sZ[g], sN[g]);
        }
        f32x4 aR[2], aZ[2];
        #pragma unroll
        for (int g = 0; g < 2; ++g) {
            aR[g] = sR[g] + iR[g];
            aZ[g] = sZ[g] + iZ[g];
        }
        gate4x2(aR, aZ, iN, sN, hf);
        #pragma unroll
        for (int g = 0; g < 2; ++g) {
            s16x4 hi4, lo4;
            split4_tr(f32x4{hf[g][0], hf[g][1], hf[g][2], hf[g][3]}, hi4, lo4);
            pubH_[g][m][1][1][lane] = __builtin_bit_cast(ull, hi4);   // h1[511]
            pubL_[g][m][1][1][lane] = __builtin_bit_cast(ull, lo4);
        }
    }
    __syncthreads();

    if (wid >= 2) {
        // projection, one group per L1 wave: wid2 -> group 0, wid3 -> group 1
        const int g = m;
        bf16x8 Hh = combine8(pubH_[g][0][1][1][lane], pubH_[g][1][1][1][lane]);
        bf16x8 Hl = combine8(pubL_[g][0][1][1][lane], pubL_[g][1][1][1][lane]);
        const float* pp = W_proj + r16 * 32 + 4 * q;
        bf16x8 Wph, Wpl;
        split8_tr(*(const f32x4*)pp, *(const f32x4*)(pp + 16), Wph, Wpl);
        f32x4 accp = *(const f32x4*)(b_proj + 4 * q);   // elem reg -> output 4q+reg
        accp = MFMA(Wph, Hh, accp);
        accp = MFMA(Wph, Hl, accp);
        accp = MFMA(Wpl, Hh, accp);
        #pragma unroll
        for (int rg = 0; rg < 4; ++rg)
            out[(b0 + 16 * g + r16) * 16 + 4 * q + rg] = accp[rg];
    }
}

extern "C" void kernel_launch(void* const* d_in, const int* in_sizes, int n_in,
                              void* d_out, int out_size, void* d_ws, size_t ws_size,
                              hipStream_t stream) {
    const float* x      = (const float*)d_in[0];
    const float* W_ih0  = (const float*)d_in[1];
    const float* W_hh0  = (const float*)d_in[2];
    const float* b_ih0  = (const float*)d_in[3];
    const float* b_hh0  = (const float*)d_in[4];
    const float* W_ih1  = (const float*)d_in[5];
    const float* W_hh1  = (const float*)d_in[6];
    const float* b_ih1  = (const float*)d_in[7];
    const float* b_hh1  = (const float*)d_in[8];
    const float* W_proj = (const float*)d_in[9];
    const float* b_proj = (const float*)d_in[10];
    float* out = (float*)d_out;

    const int nb   = in_sizes[0] / (T_SEQ * 32);   // 4096 batch elements
    const int grid = nb / 32;                      // 32 batches per 4-wave block

    hipLaunchKernelGGL(gru2_quad2, dim3(grid), dim3(256), 0, stream,
                       x, W_ih0, W_hh0, b_ih0, b_hh0,
                       W_ih1, W_hh1, b_ih1, b_hh1, W_proj, b_proj, out);
}

// Round 15
// 433.059 us; speedup vs baseline: 1.1361x; 1.1361x over previous
//
#include <hip/hip_runtime.h>

using bf16x8 = __attribute__((ext_vector_type(8))) short;
using short8 = __attribute__((ext_vector_type(8))) short;
using f32x4  = __attribute__((ext_vector_type(4))) float;
using u32x4  = __attribute__((ext_vector_type(4))) unsigned;

#define T_SEQ 512
#define KS 4                       // timesteps per barrier interval
#define NBLK (T_SEQ / KS)          // 128 blocks of KS steps
#define MFMA(A, B, C) __builtin_amdgcn_mfma_f32_16x16x32_bf16((A), (B), (C), 0, 0, 0)

// Raw barrier: lgkmcnt(0) makes this wave's ds_write visible; no vmcnt drain.
#define BARRIER()                                            \
    do {                                                     \
        __builtin_amdgcn_sched_barrier(0);                   \
        asm volatile("s_waitcnt lgkmcnt(0)" ::: "memory");   \
        __builtin_amdgcn_s_barrier();                        \
        __builtin_amdgcn_sched_barrier(0);                   \
    } while (0)

static constexpr float NL2E  = -1.44269504f;   // -log2(e)
static constexpr float N2L2E = -2.88539008f;   // -2*log2(e)

// Truncation split: hi = bf16-truncate(v), lo = bf16-truncate(v - hi) (exact residual).
__device__ __forceinline__ void split8_tr(f32x4 a, f32x4 b, bf16x8& hi, bf16x8& lo) {
    u32x4 ua = __builtin_bit_cast(u32x4, a);
    u32x4 ub = __builtin_bit_cast(u32x4, b);
    u32x4 m  = {0xffff0000u, 0xffff0000u, 0xffff0000u, 0xffff0000u};
    f32x4 ra = a - __builtin_bit_cast(f32x4, ua & m);
    f32x4 rb = b - __builtin_bit_cast(f32x4, ub & m);
    short8 sa  = __builtin_bit_cast(short8, a);
    short8 sb  = __builtin_bit_cast(short8, b);
    short8 sra = __builtin_bit_cast(short8, ra);
    short8 srb = __builtin_bit_cast(short8, rb);
    hi = __builtin_shufflevector(sa, sb, 1, 3, 5, 7, 9, 11, 13, 15);
    lo = __builtin_shufflevector(sra, srb, 1, 3, 5, 7, 9, 11, 13, 15);
}

__device__ __forceinline__ void pack_frag_tr(const float (&hf)[8], bf16x8& hi, bf16x8& lo) {
    f32x4 a = {hf[0], hf[1], hf[2], hf[3]};
    f32x4 b = {hf[4], hf[5], hf[6], hf[7]};
    split8_tr(a, b, hi, lo);
}

// 18-MFMA full-layer product block: 6 independent acc chains, 3 rounds.
__device__ __forceinline__ void mfma18(const bf16x8 (&WH)[6], const bf16x8 (&WL)[6],
                                       bf16x8 inh, bf16x8 inl,
                                       const f32x4 (&C)[6], f32x4 (&A)[6]) {
    #pragma unroll
    for (int t = 0; t < 6; ++t) A[t] = MFMA(WH[t], inh, C[t]);
    #pragma unroll
    for (int t = 0; t < 6; ++t) A[t] = MFMA(WH[t], inl, A[t]);
    #pragma unroll
    for (int t = 0; t < 6; ++t) A[t] = MFMA(WL[t], inh, A[t]);
}

// Gates for 8 units (full layer per lane), level-major.
// Tiles: 0,1 = r; 2,3 = z; 4,5 = n. iA has biases folded (rz: b_ih+b_hh; n: b_ih).
// sA n-tiles carry b_hh-n via C-in.
__device__ __forceinline__ void gate8f(const f32x4 (&iA)[6], const f32x4 (&sA)[6],
                                       float (&hf)[8]) {
    f32x4 aR0 = iA[0] + sA[0], aR1 = iA[1] + sA[1];
    f32x4 aZ0 = iA[2] + sA[2], aZ1 = iA[3] + sA[3];
    float er[8], ez[8];
    #pragma unroll
    for (int j = 0; j < 4; ++j) {
        er[j]     = __builtin_amdgcn_exp2f(aR0[j] * NL2E);
        er[4 + j] = __builtin_amdgcn_exp2f(aR1[j] * NL2E);
        ez[j]     = __builtin_amdgcn_exp2f(aZ0[j] * NL2E);
        ez[4 + j] = __builtin_amdgcn_exp2f(aZ1[j] * NL2E);
    }
    float gr[8], gz[8];
    #pragma unroll
    for (int e = 0; e < 8; ++e) gr[e] = __builtin_amdgcn_rcpf(1.f + er[e]);
    #pragma unroll
    for (int e = 0; e < 8; ++e) gz[e] = __builtin_amdgcn_rcpf(1.f + ez[e]);
    float en[8];
    #pragma unroll
    for (int e = 0; e < 8; ++e) {
        const int s = e >> 2, j = e & 3;
        float u = fmaf(gr[e], sA[4 + s][j], iA[4 + s][j]);
        en[e] = __builtin_amdgcn_exp2f(fminf(u * N2L2E, 126.f));
    }
    float qn[8];
    #pragma unroll
    for (int e = 0; e < 8; ++e) qn[e] = __builtin_amdgcn_rcpf(1.f + en[e]);
    #pragma unroll
    for (int e = 0; e < 8; ++e) {
        float nn = fmaf(en[e] * qn[e], -2.f, 1.f);
        hf[e] = fmaf(gz[e], hf[e] - nn, nn);
    }
}

// Block = 128 threads = 2 full-layer waves (w0: layer0, w1: layer1, lag KS).
// A full-layer wave is SELF-SUFFICIENT: its gate output (units {4q+j,16+4q+j})
// is exactly its own next-step B-frag -> KS recurrence steps run back-to-back
// in registers with NO barrier and NO LDS on the chain. Only the L0->L1
// handoff crosses LDS, once per KS-block (barriers: 512 -> NBLK+1 = 129).
// R13/R14 isolated a ~800-1300cyc per-barrier-interval fixed cost; this
// structure pays it once per 4 steps instead of every step.
// Frag map: batch = b0+(lane&15), q = lane>>4; elems 0..3 = units 4q+j,
// 4..7 = 16+4q+j (same map A and B). D: col=lane&15, row=4q+reg (m89).
__global__ __launch_bounds__(128, 1)
void gru2_kpipe(const float* __restrict__ x,
                const float* __restrict__ W_ih0, const float* __restrict__ W_hh0,
                const float* __restrict__ b_ih0, const float* __restrict__ b_hh0,
                const float* __restrict__ W_ih1, const float* __restrict__ W_hh1,
                const float* __restrict__ b_ih1, const float* __restrict__ b_hh1,
                const float* __restrict__ W_proj, const float* __restrict__ b_proj,
                float* __restrict__ out)
{
    const int tid  = threadIdx.x;
    const int wid  = tid >> 6;        // 0: layer0 wave, 1: layer1 wave
    const int lane = tid & 63;
    const int r16  = lane & 15;
    const int q    = lane >> 4;
    const int b0   = blockIdx.x * 16;

    // h0 handoff: [parity][step-in-block][lane], hi and lo frags (16 KB)
    __shared__ u32x4 pubHi[2][KS][64];
    __shared__ u32x4 pubLo[2][KS][64];

    const float* Wx = wid ? W_ih1 : W_ih0;
    const float* Wh = wid ? W_hh1 : W_hh0;
    const float* bx = wid ? b_ih1 : b_ih0;
    const float* bh = wid ? b_hh1 : b_hh0;

    // full-layer weights: 6 M-tiles (0,1=r; 2,3=z; 4,5=n), hi/lo split
    bf16x8 WxH[6], WxL[6], WhH[6], WhL[6];
    f32x4 iC[6], sC[6];
    #pragma unroll
    for (int t = 0; t < 6; ++t) {
        const float* p1 = Wx + (16 * t + r16) * 32 + 4 * q;
        split8_tr(*(const f32x4*)p1, *(const f32x4*)(p1 + 16), WxH[t], WxL[t]);
        const float* p2 = Wh + (16 * t + r16) * 32 + 4 * q;
        split8_tr(*(const f32x4*)p2, *(const f32x4*)(p2 + 16), WhH[t], WhL[t]);
        if (t < 4) {  // r,z: fold both biases into input-side C; state C = 0
            iC[t] = *(const f32x4*)(bx + 16 * t + 4 * q) + *(const f32x4*)(bh + 16 * t + 4 * q);
            sC[t] = f32x4{0.f, 0.f, 0.f, 0.f};
        } else {      // n: keep sides separate
            iC[t] = *(const f32x4*)(bx + 16 * t + 4 * q);
            sC[t] = *(const f32x4*)(bh + 16 * t + 4 * q);
        }
    }

    float hf[8] = {};
    bf16x8 Hh = {}, Hl = {};           // register-resident state frag (h[-1] = 0)

    const float* xp = x + (size_t)(b0 + r16) * (T_SEQ * 32) + 4 * q;
    f32x4 xcA[KS], xcB[KS], xnA[KS], xnB[KS];
    if (wid == 0) {
        #pragma unroll
        for (int kk = 0; kk < KS; ++kk) {          // block 0 (current)
            xcA[kk] = *(const f32x4*)(xp + kk * 32);
            xcB[kk] = *(const f32x4*)(xp + kk * 32 + 16);
        }
        #pragma unroll
        for (int kk = 0; kk < KS; ++kk) {          // block 1 (in flight)
            xnA[kk] = *(const f32x4*)(xp + (KS + kk) * 32);
            xnB[kk] = *(const f32x4*)(xp + (KS + kk) * 32 + 16);
        }
    }

    #pragma unroll 1
    for (int blk = 0; blk <= NBLK; ++blk) {
        if (wid == 0) {
            if (blk < NBLK) {
                const int par = blk & 1;
                #pragma unroll
                for (int kk = 0; kk < KS; ++kk) {
                    bf16x8 xh, xl;
                    split8_tr(xcA[kk], xcB[kk], xh, xl);
                    f32x4 sA[6], iA[6];
                    mfma18(WhH, WhL, Hh, Hl, sC, sA);   // chain head (state)
                    mfma18(WxH, WxL, xh, xl, iC, iA);   // fills chain stalls
                    gate8f(iA, sA, hf);
                    pack_frag_tr(hf, Hh, Hl);
                    pubHi[par][kk][lane] = __builtin_bit_cast(u32x4, Hh);
                    pubLo[par][kk][lane] = __builtin_bit_cast(u32x4, Hl);
                }
                // rotate prefetch: xn -> xc, issue block blk+2 (full interval of cover)
                #pragma unroll
                for (int kk = 0; kk < KS; ++kk) { xcA[kk] = xnA[kk]; xcB[kk] = xnB[kk]; }
                const int nb2 = (blk + 2 < NBLK) ? blk + 2 : NBLK - 1;
                #pragma unroll
                for (int kk = 0; kk < KS; ++kk) {
                    xnA[kk] = *(const f32x4*)(xp + (size_t)(nb2 * KS + kk) * 32);
                    xnB[kk] = *(const f32x4*)(xp + (size_t)(nb2 * KS + kk) * 32 + 16);
                }
            }
        } else {
            if (blk >= 1) {
                const int b2  = blk - 1;
                const int par = b2 & 1;
                u32x4 fH[KS], fL[KS];
                #pragma unroll
                for (int kk = 0; kk < KS; ++kk) {   // all handoff reads up-front
                    fH[kk] = pubHi[par][kk][lane];
                    fL[kk] = pubLo[par][kk][lane];
                }
                #pragma unroll
                for (int kk = 0; kk < KS; ++kk) {
                    bf16x8 inh = __builtin_bit_cast(bf16x8, fH[kk]);
                    bf16x8 inl = __builtin_bit_cast(bf16x8, fL[kk]);
                    f32x4 sA[6], iA[6];
                    mfma18(WhH, WhL, Hh, Hl, sC, sA);
                    mfma18(WxH, WxL, inh, inl, iC, iA);
                    gate8f(iA, sA, hf);
                    pack_frag_tr(hf, Hh, Hl);
                }
            }
        }
        BARRIER();
    }

    if (wid == 1) {
        // projection: out[b][o] = b_proj[o] + sum_u W_proj[o][u] * h1[u]
        const float* pp = W_proj + r16 * 32 + 4 * q;
        bf16x8 Wph, Wpl;
        split8_tr(*(const f32x4*)pp, *(const f32x4*)(pp + 16), Wph, Wpl);
        f32x4 accp = *(const f32x4*)(b_proj + 4 * q);   // elem reg -> output 4q+reg
        accp = MFMA(Wph, Hh, accp);
        accp = MFMA(Wph, Hl, accp);
        accp = MFMA(Wpl, Hh, accp);
        #pragma unroll
        for (int rg = 0; rg < 4; ++rg)
            out[(b0 + r16) * 16 + 4 * q + rg] = accp[rg];
    }
}

extern "C" void kernel_launch(void* const* d_in, const int* in_sizes, int n_in,
                              void* d_out, int out_size, void* d_ws, size_t ws_size,
                              hipStream_t stream) {
    const float* x      = (const float*)d_in[0];
    const float* W_ih0  = (const float*)d_in[1];
    const float* W_hh0  = (const float*)d_in[2];
    const float* b_ih0  = (const float*)d_in[3];
    const float* b_hh0  = (const float*)d_in[4];
    const float* W_ih1  = (const float*)d_in[5];
    const float* W_hh1  = (const float*)d_in[6];
    const float* b_ih1  = (const float*)d_in[7];
    const float* b_hh1  = (const float*)d_in[8];
    const float* W_proj = (const float*)d_in[9];
    const float* b_proj = (const float*)d_in[10];
    float* out = (float*)d_out;

    const int nb   = in_sizes[0] / (T_SEQ * 32);   // 4096 batch elements
    const int grid = nb / 16;                      // 16 batches per 2-wave block

    hipLaunchKernelGGL(gru2_kpipe, dim3(grid), dim3(128), 0, stream,
                       x, W_ih0, W_hh0, b_ih0, b_hh0,
                       W_ih1, W_hh1, b_ih1, b_hh1, W_proj, b_proj, out);
}

// Round 16
// 387.752 us; speedup vs baseline: 1.2689x; 1.1168x over previous
//
#include <hip/hip_runtime.h>

using bf16x8 = __attribute__((ext_vector_type(8))) short;
using short8 = __attribute__((ext_vector_type(8))) short;
using s16x4  = __attribute__((ext_vector_type(4))) short;
using f32x4  = __attribute__((ext_vector_type(4))) float;
using u32x4  = __attribute__((ext_vector_type(4))) unsigned;
using ull    = unsigned long long;

#define T_SEQ 512
#define MFMA(A, B, C) __builtin_amdgcn_mfma_f32_16x16x32_bf16((A), (B), (C), 0, 0, 0)

// Raw barrier: lgkmcnt(0) makes this wave's ds_write visible; no vmcnt drain.
#define BARRIER()                                            \
    do {                                                     \
        __builtin_amdgcn_sched_barrier(0);                   \
        asm volatile("s_waitcnt lgkmcnt(0)" ::: "memory");   \
        __builtin_amdgcn_s_barrier();                        \
        __builtin_amdgcn_sched_barrier(0);                   \
    } while (0)

static constexpr float NL2E  = -1.44269504f;   // -log2(e)
static constexpr float N2L2E = -2.88539008f;   // -2*log2(e)

// Truncation split: hi = bf16-truncate(v), lo = bf16-truncate(v - hi) (exact residual).
__device__ __forceinline__ void split8_tr(f32x4 a, f32x4 b, bf16x8& hi, bf16x8& lo) {
    u32x4 ua = __builtin_bit_cast(u32x4, a);
    u32x4 ub = __builtin_bit_cast(u32x4, b);
    u32x4 m  = {0xffff0000u, 0xffff0000u, 0xffff0000u, 0xffff0000u};
    f32x4 ra = a - __builtin_bit_cast(f32x4, ua & m);
    f32x4 rb = b - __builtin_bit_cast(f32x4, ub & m);
    short8 sa  = __builtin_bit_cast(short8, a);
    short8 sb  = __builtin_bit_cast(short8, b);
    short8 sra = __builtin_bit_cast(short8, ra);
    short8 srb = __builtin_bit_cast(short8, rb);
    hi = __builtin_shufflevector(sa, sb, 1, 3, 5, 7, 9, 11, 13, 15);
    lo = __builtin_shufflevector(sra, srb, 1, 3, 5, 7, 9, 11, 13, 15);
}

__device__ __forceinline__ void split4_tr(f32x4 a, s16x4& hi, s16x4& lo) {
    u32x4 ua = __builtin_bit_cast(u32x4, a);
    u32x4 m  = {0xffff0000u, 0xffff0000u, 0xffff0000u, 0xffff0000u};
    f32x4 ra = a - __builtin_bit_cast(f32x4, ua & m);
    short8 sa  = __builtin_bit_cast(short8, a);
    short8 sra = __builtin_bit_cast(short8, ra);
    hi = __builtin_shufflevector(sa, sa, 1, 3, 5, 7);
    lo = __builtin_shufflevector(sra, sra, 1, 3, 5, 7);
}

__device__ __forceinline__ bf16x8 combine8(ull lo8, ull hi8) {
    u32x4 v = {(unsigned)lo8, (unsigned)(lo8 >> 32),
               (unsigned)hi8, (unsigned)(hi8 >> 32)};
    return __builtin_bit_cast(bf16x8, v);
}
__device__ __forceinline__ bf16x8 combine8_sel(ull own, ull other, int m) {
    return combine8(m ? other : own, m ? own : other);
}

// 9-MFMA product block: 3 independent acc chains (hiW*hi, hiW*lo, loW*hi).
__device__ __forceinline__ void mfma9(const bf16x8 (&WH)[3], const bf16x8 (&WL)[3],
                                      bf16x8 inh, bf16x8 inl,
                                      f32x4 c0, f32x4 c1, f32x4 c2,
                                      f32x4& a0, f32x4& a1, f32x4& a2) {
    a0 = MFMA(WH[0], inh, c0); a1 = MFMA(WH[1], inh, c1); a2 = MFMA(WH[2], inh, c2);
    a0 = MFMA(WH[0], inl, a0); a1 = MFMA(WH[1], inl, a1); a2 = MFMA(WH[2], inl, a2);
    a0 = MFMA(WL[0], inh, a0); a1 = MFMA(WL[1], inh, a1); a2 = MFMA(WL[2], inh, a2);
}

// Gates for this wave's 4 hidden units; level-major 4-wide.
__device__ __forceinline__ void gate4(f32x4 aR, f32x4 aZ, f32x4 iN, f32x4 sN,
                                      float (&hf)[4]) {
    float er[4], ez[4];
    #pragma unroll
    for (int j = 0; j < 4; ++j) er[j] = __builtin_amdgcn_exp2f(aR[j] * NL2E);
    #pragma unroll
    for (int j = 0; j < 4; ++j) ez[j] = __builtin_amdgcn_exp2f(aZ[j] * NL2E);
    float gr[4], gz[4];
    #pragma unroll
    for (int j = 0; j < 4; ++j) gr[j] = __builtin_amdgcn_rcpf(1.f + er[j]);
    #pragma unroll
    for (int j = 0; j < 4; ++j) gz[j] = __builtin_amdgcn_rcpf(1.f + ez[j]);
    float en[4];
    #pragma unroll
    for (int j = 0; j < 4; ++j) {
        float u = fmaf(gr[j], sN[j], iN[j]);
        en[j] = __builtin_amdgcn_exp2f(fminf(u * N2L2E, 126.f));
    }
    float qn[4];
    #pragma unroll
    for (int j = 0; j < 4; ++j) qn[j] = __builtin_amdgcn_rcpf(1.f + en[j]);
    #pragma unroll
    for (int j = 0; j < 4; ++j) {
        float nn = fmaf(en[j] * qn[j], -2.f, 1.f);
        hf[j] = fmaf(gz[j], hf[j] - nn, nn);
    }
}

// Block = 512 threads = 8 waves = TWO independent 4-wave R9 groups (batch
// groups g=0,1), fused so each SIMD holds 2 waves with UNCORRELATED chains.
// Rationale (R7-R15 evidence): per-step wall has a ~1100cyc component that
// survives barrier/LDS/conflict/remat fixes -> in-order waves stall with no
// SIMD-mate to issue; the only wins so far (R7, R9) added waves. R13's 2/SIMD
// failed (producer-consumer lockstep); R14's within-wave G=2 failed (in-order
// serialization). Here the HW round-robins 2 independent waves per SIMD:
// group A's stalls are filled by group B's issue -> ~2x throughput at equal
// interval length. Within a group, identical to the R12 kernel.
// Frag map: batch = b0+(lane&15), q = lane>>4; elems 0..3 = units 4q+j,
// 4..7 = 16+4q+j (same map A and B). D: col=lane&15, row=4q+reg (m89).
__global__ __launch_bounds__(512, 1)
void gru2_dual4(const float* __restrict__ x,
                const float* __restrict__ W_ih0, const float* __restrict__ W_hh0,
                const float* __restrict__ b_ih0, const float* __restrict__ b_hh0,
                const float* __restrict__ W_ih1, const float* __restrict__ W_hh1,
                const float* __restrict__ b_ih1, const float* __restrict__ b_hh1,
                const float* __restrict__ W_proj, const float* __restrict__ b_proj,
                float* __restrict__ out)
{
    const int tid  = threadIdx.x;
    const int wid  = tid >> 6;        // 0..7
    const int grp  = wid >> 2;        // batch group (independent job)
    const int role = wid & 3;
    const int L    = role >> 1;       // layer
    const int m    = role & 1;        // row half
    const int lane = tid & 63;
    const int r16  = lane & 15;
    const int q    = lane >> 4;
    const int b0   = blockIdx.x * 32 + grp * 16;

    // [group][half][layer][parity][lane] (8B each) -> 8KB + 8KB
    __shared__ ull pubH_[2][2][2][2][64];
    __shared__ ull pubL_[2][2][2][2][64];

    const float* Wx = L ? W_ih1 : W_ih0;
    const float* Wh = L ? W_hh1 : W_hh0;
    const float* bx = L ? b_ih1 : b_ih0;
    const float* bh = L ? b_hh1 : b_hh0;

    // weight fragments for tiles {m, 2+m, 4+m}; g: 0=r, 1=z, 2=n
    bf16x8 WxH[3], WxL[3], WhH[3], WhL[3];
    f32x4 bxf[3], bhf[3];
    #pragma unroll
    for (int g = 0; g < 3; ++g) {
        const int tile = 2 * g + m;
        const float* p1 = Wx + (16 * tile + r16) * 32 + 4 * q;
        split8_tr(*(const f32x4*)p1, *(const f32x4*)(p1 + 16), WxH[g], WxL[g]);
        const float* p2 = Wh + (16 * tile + r16) * 32 + 4 * q;
        split8_tr(*(const f32x4*)p2, *(const f32x4*)(p2 + 16), WhH[g], WhL[g]);
        bxf[g] = *(const f32x4*)(bx + 16 * tile + 4 * q);
        bhf[g] = *(const f32x4*)(bh + 16 * tile + 4 * q);
    }

    float hf[4] = {0.f, 0.f, 0.f, 0.f};
    ull ownH = 0, ownL = 0;
    const float* xp = x + (size_t)(b0 + r16) * (T_SEQ * 32) + 4 * q;
    f32x4 xA = {}, xB = {};
    bf16x8 xh_cur = {}, xl_cur = {};

    if (L == 0) {
        f32x4 x0A = *(const f32x4*)(xp);
        f32x4 x0B = *(const f32x4*)(xp + 16);
        xA = *(const f32x4*)(xp + 32);         // x[1] in flight
        xB = *(const f32x4*)(xp + 48);
        split8_tr(x0A, x0B, xh_cur, xl_cur);   // x[0]
        // prologue: h0[0] from x[0], state = 0 (state accs = b_hh frags)
        f32x4 iR, iZ, iN;
        mfma9(WxH, WxL, xh_cur, xl_cur, bxf[0], bxf[1], bxf[2], iR, iZ, iN);
        gate4(iR + bhf[0], iZ + bhf[1], iN, bhf[2], hf);
        s16x4 hi4, lo4;
        split4_tr(f32x4{hf[0], hf[1], hf[2], hf[3]}, hi4, lo4);
        ownH = __builtin_bit_cast(ull, hi4);
        ownL = __builtin_bit_cast(ull, lo4);
        pubH_[grp][m][0][0][lane] = ownH;      // publish h0[0] half
        pubL_[grp][m][0][0][lane] = ownL;
        split8_tr(xA, xB, xh_cur, xl_cur);     // x[1] -> cur for iter 1
        xA = *(const f32x4*)(xp + 64);         // x[2] in flight
        xB = *(const f32x4*)(xp + 80);
    } else {
        // zero h1's initial state slot (read at t=1 as parity 1)
        pubH_[grp][m][1][1][lane] = 0;
        pubL_[grp][m][1][1][lane] = 0;
    }

    // ---- main loop: wave (g,0,m) -> h0[t] half, wave (g,1,m) -> h1[t-1] half ----
    #pragma unroll 1
    for (int t = 1; t < T_SEQ; ++t) {
        BARRIER();                       // prev-iter LDS pubs visible; no vmcnt drain
        const int pPrev = (t - 1) & 1;
        const int pCur  = t & 1;
        f32x4 iR, iZ, iN, sR, sZ, sN;
        if (L == 0) {
            ull oH = pubH_[grp][1 - m][0][pPrev][lane];   // other h0 half (8B)
            ull oL = pubL_[grp][1 - m][0][pPrev][lane];
            // input MFMAs start immediately: xh_cur pre-split last iteration
            mfma9(WxH, WxL, xh_cur, xl_cur, bxf[0], bxf[1], bxf[2], iR, iZ, iN);
            bf16x8 Sh = combine8_sel(ownH, oH, m);        // waits lgkmcnt here
            bf16x8 Sl = combine8_sel(ownL, oL, m);
            mfma9(WhH, WhL, Sh, Sl, bhf[0], bhf[1], bhf[2], sR, sZ, sN);
            split8_tr(xA, xB, xh_cur, xl_cur);            // x[t+1] (load 1 iter old)
            const int tn = (t + 2 < T_SEQ) ? t + 2 : T_SEQ - 1;
            xA = *(const f32x4*)(xp + (size_t)tn * 32);   // x[t+2] in flight
            xB = *(const f32x4*)(xp + (size_t)tn * 32 + 16);
        } else {
            ull i0H = pubH_[grp][0][0][pPrev][lane];      // h0[t-1] halves (input)
            ull i1H = pubH_[grp][1][0][pPrev][lane];
            ull i0L = pubL_[grp][0][0][pPrev][lane];
            ull i1L = pubL_[grp][1][0][pPrev][lane];
            ull oH  = pubH_[grp][1 - m][1][pCur][lane];   // other h1[t-2] half
            ull oL  = pubL_[grp][1 - m][1][pCur][lane];
            bf16x8 inh = combine8(i0H, i1H);
            bf16x8 inl = combine8(i0L, i1L);
            mfma9(WxH, WxL, inh, inl, bxf[0], bxf[1], bxf[2], iR, iZ, iN);
            bf16x8 Sh = combine8_sel(ownH, oH, m);
            bf16x8 Sl = combine8_sel(ownL, oL, m);
            mfma9(WhH, WhL, Sh, Sl, bhf[0], bhf[1], bhf[2], sR, sZ, sN);
        }

        gate4(sR + iR, sZ + iZ, iN, sN, hf);

        s16x4 hi4, lo4;
        split4_tr(f32x4{hf[0], hf[1], hf[2], hf[3]}, hi4, lo4);
        ownH = __builtin_bit_cast(ull, hi4);
        ownL = __builtin_bit_cast(ull, lo4);
        const int pW = (L == 0) ? pCur : pPrev;   // L0 writes h0[t], L1 h1[t-1]
        pubH_[grp][m][L][pW][lane] = ownH;
        pubL_[grp][m][L][pW][lane] = ownL;
    }

    __syncthreads();                     // h0[511] (p1), h1[510] (p0) visible
    if (L == 1) {
        // final step: h1[511] from h0[511] and h1[510]
        bf16x8 inh = combine8(pubH_[grp][0][0][1][lane], pubH_[grp][1][0][1][lane]);
        bf16x8 inl = combine8(pubL_[grp][0][0][1][lane], pubL_[grp][1][0][1][lane]);
        bf16x8 Sh  = combine8_sel(ownH, pubH_[grp][1 - m][1][0][lane], m);
        bf16x8 Sl  = combine8_sel(ownL, pubL_[grp][1 - m][1][0][lane], m);
        f32x4 iR, iZ, iN, sR, sZ, sN;
        mfma9(WxH, WxL, inh, inl, bxf[0], bxf[1], bxf[2], iR, iZ, iN);
        mfma9(WhH, WhL, Sh, Sl, bhf[0], bhf[1], bhf[2], sR, sZ, sN);
        gate4(sR + iR, sZ + iZ, iN, sN, hf);
        s16x4 hi4, lo4;
        split4_tr(f32x4{hf[0], hf[1], hf[2], hf[3]}, hi4, lo4);
        pubH_[grp][m][1][1][lane] = __builtin_bit_cast(ull, hi4);   // h1[511]
        pubL_[grp][m][1][1][lane] = __builtin_bit_cast(ull, lo4);
    }
    __syncthreads();

    if (role == 2) {
        // projection (one wave per group): out[b][o] = b_proj[o] + W_proj[o]*h1
        bf16x8 Hh = combine8(pubH_[grp][0][1][1][lane], pubH_[grp][1][1][1][lane]);
        bf16x8 Hl = combine8(pubL_[grp][0][1][1][lane], pubL_[grp][1][1][1][lane]);
        const float* pp = W_proj + r16 * 32 + 4 * q;
        bf16x8 Wph, Wpl;
        split8_tr(*(const f32x4*)pp, *(const f32x4*)(pp + 16), Wph, Wpl);
        f32x4 accp = *(const f32x4*)(b_proj + 4 * q);   // elem reg -> output 4q+reg
        accp = MFMA(Wph, Hh, accp);
        accp = MFMA(Wph, Hl, accp);
        accp = MFMA(Wpl, Hh, accp);
        #pragma unroll
        for (int rg = 0; rg < 4; ++rg)
            out[(b0 + r16) * 16 + 4 * q + rg] = accp[rg];
    }
}

extern "C" void kernel_launch(void* const* d_in, const int* in_sizes, int n_in,
                              void* d_out, int out_size, void* d_ws, size_t ws_size,
                              hipStream_t stream) {
    const float* x      = (const float*)d_in[0];
    const float* W_ih0  = (const float*)d_in[1];
    const float* W_hh0  = (const float*)d_in[2];
    const float* b_ih0  = (const float*)d_in[3];
    const float* b_hh0  = (const float*)d_in[4];
    const float* W_ih1  = (const float*)d_in[5];
    const float* W_hh1  = (const float*)d_in[6];
    const float* b_ih1  = (const float*)d_in[7];
    const float* b_hh1  = (const float*)d_in[8];
    const float* W_proj = (const float*)d_in[9];
    const float* b_proj = (const float*)d_in[10];
    float* out = (float*)d_out;

    const int nb   = in_sizes[0] / (T_SEQ * 32);   // 4096 batch elements
    const int grid = nb / 32;                      // 32 batches per 8-wave block

    hipLaunchKernelGGL(gru2_dual4, dim3(grid), dim3(512), 0, stream,
                       x, W_ih0, W_hh0, b_ih0, b_hh0,
                       W_ih1, W_hh1, b_ih1, b_hh1, W_proj, b_proj, out);
}

// Round 17
// 330.496 us; speedup vs baseline: 1.4887x; 1.1732x over previous
//
#include <hip/hip_runtime.h>

using bf16x8 = __attribute__((ext_vector_type(8))) short;
using short8 = __attribute__((ext_vector_type(8))) short;
using s16x4  = __attribute__((ext_vector_type(4))) short;
using f32x4  = __attribute__((ext_vector_type(4))) float;
using u32x4  = __attribute__((ext_vector_type(4))) unsigned;
using ull    = unsigned long long;

#define T_SEQ 512
#define MFMA(A, B, C) __builtin_amdgcn_mfma_f32_16x16x32_bf16((A), (B), (C), 0, 0, 0)

static constexpr float NL2E  = -1.44269504f;   // -log2(e): r,z rows pre-scaled
static constexpr float N2L2E = -2.88539008f;   // -2*log2(e): n rows pre-scaled

// Truncation split: hi = bf16-truncate(v), lo = bf16-truncate(v - hi) (exact residual).
__device__ __forceinline__ void split8_tr(f32x4 a, f32x4 b, bf16x8& hi, bf16x8& lo) {
    u32x4 ua = __builtin_bit_cast(u32x4, a);
    u32x4 ub = __builtin_bit_cast(u32x4, b);
    u32x4 m  = {0xffff0000u, 0xffff0000u, 0xffff0000u, 0xffff0000u};
    f32x4 ra = a - __builtin_bit_cast(f32x4, ua & m);
    f32x4 rb = b - __builtin_bit_cast(f32x4, ub & m);
    short8 sa  = __builtin_bit_cast(short8, a);
    short8 sb  = __builtin_bit_cast(short8, b);
    short8 sra = __builtin_bit_cast(short8, ra);
    short8 srb = __builtin_bit_cast(short8, rb);
    hi = __builtin_shufflevector(sa, sb, 1, 3, 5, 7, 9, 11, 13, 15);
    lo = __builtin_shufflevector(sra, srb, 1, 3, 5, 7, 9, 11, 13, 15);
}

__device__ __forceinline__ void split4_tr(f32x4 a, s16x4& hi, s16x4& lo) {
    u32x4 ua = __builtin_bit_cast(u32x4, a);
    u32x4 m  = {0xffff0000u, 0xffff0000u, 0xffff0000u, 0xffff0000u};
    f32x4 ra = a - __builtin_bit_cast(f32x4, ua & m);
    short8 sa  = __builtin_bit_cast(short8, a);
    short8 sra = __builtin_bit_cast(short8, ra);
    hi = __builtin_shufflevector(sa, sa, 1, 3, 5, 7);
    lo = __builtin_shufflevector(sra, sra, 1, 3, 5, 7);
}

// Gates for 4 hidden units. ALL pre-acts arrive PRE-SCALED (r,z by -log2e;
// n-side by -2log2e), so exps are direct exp2 — one fewer level per exp.
// Critical path: exp2 -> rcp -> fma -> min -> exp2 -> rcp -> 2 fma.
__device__ __forceinline__ void gate4s(f32x4 aR, f32x4 aZ, f32x4 iN, f32x4 sN,
                                       float (&hf)[4]) {
    float er[4], ez[4];
    #pragma unroll
    for (int j = 0; j < 4; ++j) er[j] = __builtin_amdgcn_exp2f(aR[j]);
    #pragma unroll
    for (int j = 0; j < 4; ++j) ez[j] = __builtin_amdgcn_exp2f(aZ[j]);
    float gr[4], gz[4];
    #pragma unroll
    for (int j = 0; j < 4; ++j) gr[j] = __builtin_amdgcn_rcpf(1.f + er[j]);
    #pragma unroll
    for (int j = 0; j < 4; ++j) gz[j] = __builtin_amdgcn_rcpf(1.f + ez[j]);
    float en[4];
    #pragma unroll
    for (int j = 0; j < 4; ++j) {
        float u = fmaf(gr[j], sN[j], iN[j]);    // already x(-2log2e)
        en[j] = __builtin_amdgcn_exp2f(fminf(u, 126.f));
    }
    float qn[4];
    #pragma unroll
    for (int j = 0; j < 4; ++j) qn[j] = __builtin_amdgcn_rcpf(1.f + en[j]);
    #pragma unroll
    for (int j = 0; j < 4; ++j) {
        float nn = fmaf(en[j] * qn[j], -2.f, 1.f);
        hf[j] = fmaf(gz[j], hf[j] - nn, nn);
    }
}

// Block = 256 threads = 4 waves = (layer L, row-half m) — R9's structure
// (fastest measured: 292us), with the per-step chain FLATTENED:
//  - 9+9 MFMAs as 18 INDEPENDENT accumulators (1 MFMA dep-level, was 3),
//    merged by packed-add trees (R15 decomposition: chain latency dominates;
//    dep-LEVEL count is the cost, not op count).
//  - r,z weight rows and biases pre-scaled by -log2e, n rows by -2log2e:
//    exp2 consumes pre-acts directly (kills one VALU level per exp).
// Frag map: batch = b0+(lane&15), q = lane>>4; elems 0..3 = units 4q+j,
// 4..7 = 16+4q+j (same map A and B). D: col=lane&15, row=4q+reg (m89).
__global__ __launch_bounds__(256, 1)
void gru2_flat(const float* __restrict__ x,
               const float* __restrict__ W_ih0, const float* __restrict__ W_hh0,
               const float* __restrict__ b_ih0, const float* __restrict__ b_hh0,
               const float* __restrict__ W_ih1, const float* __restrict__ W_hh1,
               const float* __restrict__ b_ih1, const float* __restrict__ b_hh1,
               const float* __restrict__ W_proj, const float* __restrict__ b_proj,
               float* __restrict__ out)
{
    const int tid  = threadIdx.x;
    const int wid  = tid >> 6;
    const int L    = wid >> 1;        // 0: layer0, 1: layer1
    const int m    = wid & 1;         // row half
    const int lane = tid & 63;
    const int r16  = lane & 15;
    const int q    = lane >> 4;
    const int b0   = blockIdx.x * 16;

    // publications: [layer][parity][lane][half], hi and lo bf16 halves (8 KB)
    __shared__ ull pubH[2][2][64][2];
    __shared__ ull pubL[2][2][64][2];

    const float* Wx = L ? W_ih1 : W_ih0;
    const float* Wh = L ? W_hh1 : W_hh0;
    const float* bx = L ? b_ih1 : b_ih0;
    const float* bh = L ? b_hh1 : b_hh0;

    // weight fragments for tiles {m, 2+m, 4+m}; g: 0=r, 1=z, 2=n — PRE-SCALED
    bf16x8 WxH[3], WxL[3], WhH[3], WhL[3];
    f32x4 bC[3];     // C-in biases: r,z = (b_ih+b_hh)*NL2E; n = b_ih*N2L2E
    f32x4 bhn;       // n-gate state-side bias: b_hh_n * N2L2E
    #pragma unroll
    for (int g = 0; g < 3; ++g) {
        const int tile = 2 * g + m;
        const float sc = (g < 2) ? NL2E : N2L2E;
        const float* p1 = Wx + (16 * tile + r16) * 32 + 4 * q;
        split8_tr(*(const f32x4*)p1 * sc, *(const f32x4*)(p1 + 16) * sc, WxH[g], WxL[g]);
        const float* p2 = Wh + (16 * tile + r16) * 32 + 4 * q;
        split8_tr(*(const f32x4*)p2 * sc, *(const f32x4*)(p2 + 16) * sc, WhH[g], WhL[g]);
        if (g < 2)
            bC[g] = (*(const f32x4*)(bx + 16 * tile + 4 * q)
                   + *(const f32x4*)(bh + 16 * tile + 4 * q)) * sc;
        else {
            bC[g] = *(const f32x4*)(bx + 16 * tile + 4 * q) * sc;
            bhn   = *(const f32x4*)(bh + 16 * tile + 4 * q) * sc;
        }
    }

    float hf[4] = {0.f, 0.f, 0.f, 0.f};
    bf16x8 inh = {}, inl = {};
    const float* xp = x + (size_t)(b0 + r16) * (T_SEQ * 32) + 4 * q;
    f32x4 xA = {}, xB = {};
    const f32x4 z4 = {0.f, 0.f, 0.f, 0.f};

    if (L == 0) {
        xA = *(const f32x4*)(xp);
        xB = *(const f32x4*)(xp + 16);
        // prologue: h0[0] from x[0], state = 0 (state MFMAs skipped; sN = bhn)
        split8_tr(xA, xB, inh, inl);
        xA = *(const f32x4*)(xp + 32);       // prefetch x[1]
        xB = *(const f32x4*)(xp + 48);
        f32x4 Ra = MFMA(WxH[0], inh, bC[0]), Za = MFMA(WxH[1], inh, bC[1]), Na = MFMA(WxH[2], inh, bC[2]);
        f32x4 Rb = MFMA(WxH[0], inl, z4),   Zb = MFMA(WxH[1], inl, z4),   Nb = MFMA(WxH[2], inl, z4);
        f32x4 Rc = MFMA(WxL[0], inh, z4),   Zc = MFMA(WxL[1], inh, z4),   Nc = MFMA(WxL[2], inh, z4);
        f32x4 aR = (Ra + Rb) + Rc;
        f32x4 aZ = (Za + Zb) + Zc;
        f32x4 iN = (Na + Nb) + Nc;
        gate4s(aR, aZ, iN, bhn, hf);
        s16x4 hi4, lo4;
        split4_tr(f32x4{hf[0], hf[1], hf[2], hf[3]}, hi4, lo4);
        pubH[0][0][lane][m] = __builtin_bit_cast(ull, hi4);
        pubL[0][0][lane][m] = __builtin_bit_cast(ull, lo4);
    } else {
        // zero h1's initial state buffer (read at t=1 as parity 1)
        if (m == 0) { pubH[1][1][lane][0] = 0; pubH[1][1][lane][1] = 0; }
        else        { pubL[1][1][lane][0] = 0; pubL[1][1][lane][1] = 0; }
    }

    // ---- main loop: wave (0,m) -> h0[t] half, wave (1,m) -> h1[t-1] half ----
    #pragma unroll 1
    for (int t = 1; t < T_SEQ; ++t) {
        __syncthreads();                 // iter t-1 publications visible
        const int pPrev = (t - 1) & 1;
        const int pCur  = t & 1;
        bf16x8 Sh, Sl;
        if (L == 0) {
            Sh = __builtin_bit_cast(bf16x8, *(const u32x4*)&pubH[0][pPrev][lane][0]);
            Sl = __builtin_bit_cast(bf16x8, *(const u32x4*)&pubL[0][pPrev][lane][0]);
            split8_tr(xA, xB, inh, inl); // x[t] (register) under the ds_read wait
            const float* nx = xp + (size_t)((t + 1 < T_SEQ) ? t + 1 : t) * 32;
            xA = *(const f32x4*)(nx);    // prefetch x[t+1]
            xB = *(const f32x4*)(nx + 16);
        } else {
            inh = __builtin_bit_cast(bf16x8, *(const u32x4*)&pubH[0][pPrev][lane][0]);
            inl = __builtin_bit_cast(bf16x8, *(const u32x4*)&pubL[0][pPrev][lane][0]);
            Sh  = __builtin_bit_cast(bf16x8, *(const u32x4*)&pubH[1][pCur][lane][0]);
            Sl  = __builtin_bit_cast(bf16x8, *(const u32x4*)&pubL[1][pCur][lane][0]);
        }

        // 18 INDEPENDENT MFMAs (single dependency level), then add trees.
        f32x4 iRa = MFMA(WxH[0], inh, bC[0]), iZa = MFMA(WxH[1], inh, bC[1]), iNa = MFMA(WxH[2], inh, bC[2]);
        f32x4 iRb = MFMA(WxH[0], inl, z4),   iZb = MFMA(WxH[1], inl, z4),   iNb = MFMA(WxH[2], inl, z4);
        f32x4 iRc = MFMA(WxL[0], inh, z4),   iZc = MFMA(WxL[1], inh, z4),   iNc = MFMA(WxL[2], inh, z4);
        f32x4 sRa = MFMA(WhH[0], Sh, z4),    sZa = MFMA(WhH[1], Sh, z4),    sNa = MFMA(WhH[2], Sh, bhn);
        f32x4 sRb = MFMA(WhH[0], Sl, z4),    sZb = MFMA(WhH[1], Sl, z4),    sNb = MFMA(WhH[2], Sl, z4);
        f32x4 sRc = MFMA(WhL[0], Sh, z4),    sZc = MFMA(WhL[1], Sh, z4),    sNc = MFMA(WhL[2], Sh, z4);

        f32x4 aR = ((iRa + iRb) + (iRc + sRa)) + (sRb + sRc);   // 3 add levels
        f32x4 aZ = ((iZa + iZb) + (iZc + sZa)) + (sZb + sZc);
        f32x4 iN = (iNa + iNb) + iNc;                            // 2 add levels
        f32x4 sN = (sNa + sNb) + sNc;

        gate4s(aR, aZ, iN, sN, hf);

        s16x4 hi4, lo4;
        split4_tr(f32x4{hf[0], hf[1], hf[2], hf[3]}, hi4, lo4);
        const int pW = (L == 0) ? pCur : pPrev;   // L0 writes h0[t], L1 writes h1[t-1]
        pubH[L][pW][lane][m] = __builtin_bit_cast(ull, hi4);
        pubL[L][pW][lane][m] = __builtin_bit_cast(ull, lo4);
    }

    __syncthreads();                     // h0[511] (pub0[1]), h1[510] (pub1[0]) visible
    if (L == 1) {
        // final step: h1[511] from h0[511] and h1[510]
        bf16x8 i2h = __builtin_bit_cast(bf16x8, *(const u32x4*)&pubH[0][1][lane][0]);
        bf16x8 i2l = __builtin_bit_cast(bf16x8, *(const u32x4*)&pubL[0][1][lane][0]);
        bf16x8 Sh  = __builtin_bit_cast(bf16x8, *(const u32x4*)&pubH[1][0][lane][0]);
        bf16x8 Sl  = __builtin_bit_cast(bf16x8, *(const u32x4*)&pubL[1][0][lane][0]);
        f32x4 iRa = MFMA(WxH[0], i2h, bC[0]), iZa = MFMA(WxH[1], i2h, bC[1]), iNa = MFMA(WxH[2], i2h, bC[2]);
        f32x4 iRb = MFMA(WxH[0], i2l, z4),   iZb = MFMA(WxH[1], i2l, z4),   iNb = MFMA(WxH[2], i2l, z4);
        f32x4 iRc = MFMA(WxL[0], i2h, z4),   iZc = MFMA(WxL[1], i2h, z4),   iNc = MFMA(WxL[2], i2h, z4);
        f32x4 sRa = MFMA(WhH[0], Sh, z4),    sZa = MFMA(WhH[1], Sh, z4),    sNa = MFMA(WhH[2], Sh, bhn);
        f32x4 sRb = MFMA(WhH[0], Sl, z4),    sZb = MFMA(WhH[1], Sl, z4),    sNb = MFMA(WhH[2], Sl, z4);
        f32x4 sRc = MFMA(WhL[0], Sh, z4),    sZc = MFMA(WhL[1], Sh, z4),    sNc = MFMA(WhL[2], Sh, z4);
        f32x4 aR = ((iRa + iRb) + (iRc + sRa)) + (sRb + sRc);
        f32x4 aZ = ((iZa + iZb) + (iZc + sZa)) + (sZb + sZc);
        f32x4 iN = (iNa + iNb) + iNc;
        f32x4 sN = (sNa + sNb) + sNc;
        gate4s(aR, aZ, iN, sN, hf);
        s16x4 hi4, lo4;
        split4_tr(f32x4{hf[0], hf[1], hf[2], hf[3]}, hi4, lo4);
        pubH[1][1][lane][m] = __builtin_bit_cast(ull, hi4);   // h1[511]
        pubL[1][1][lane][m] = __builtin_bit_cast(ull, lo4);
    }
    __syncthreads();

    if (wid == 2) {
        // projection (UNscaled weights): out[b][o] = b_proj[o] + W_proj[o]*h1
        bf16x8 Hh = __builtin_bit_cast(bf16x8, *(const u32x4*)&pubH[1][1][lane][0]);
        bf16x8 Hl = __builtin_bit_cast(bf16x8, *(const u32x4*)&pubL[1][1][lane][0]);
        const float* pp = W_proj + r16 * 32 + 4 * q;
        bf16x8 Wph, Wpl;
        split8_tr(*(const f32x4*)pp, *(const f32x4*)(pp + 16), Wph, Wpl);
        f32x4 accp = *(const f32x4*)(b_proj + 4 * q);   // elem reg -> output 4q+reg
        accp = MFMA(Wph, Hh, accp);
        accp = MFMA(Wph, Hl, accp);
        accp = MFMA(Wpl, Hh, accp);
        #pragma unroll
        for (int rg = 0; rg < 4; ++rg)
            out[(b0 + r16) * 16 + 4 * q + rg] = accp[rg];
    }
}

extern "C" void kernel_launch(void* const* d_in, const int* in_sizes, int n_in,
                              void* d_out, int out_size, void* d_ws, size_t ws_size,
                              hipStream_t stream) {
    const float* x      = (const float*)d_in[0];
    const float* W_ih0  = (const float*)d_in[1];
    const float* W_hh0  = (const float*)d_in[2];
    const float* b_ih0  = (const float*)d_in[3];
    const float* b_hh0  = (const float*)d_in[4];
    const float* W_ih1  = (const float*)d_in[5];
    const float* W_hh1  = (const float*)d_in[6];
    const float* b_ih1  = (const float*)d_in[7];
    const float* b_hh1  = (const float*)d_in[8];
    const float* W_proj = (const float*)d_in[9];
    const float* b_proj = (const float*)d_in[10];
    float* out = (float*)d_out;

    const int nb   = in_sizes[0] / (T_SEQ * 32);   // 4096 batch elements
    const int grid = nb / 16;                      // 16 batches per 4-wave block

    hipLaunchKernelGGL(gru2_flat, dim3(grid), dim3(256), 0, stream,
                       x, W_ih0, W_hh0, b_ih0, b_hh0,
                       W_ih1, W_hh1, b_ih1, b_hh1, W_proj, b_proj, out);
}

// Round 18
// 290.891 us; speedup vs baseline: 1.6914x; 1.1362x over previous
//
#include <hip/hip_runtime.h>

using bf16x8 = __attribute__((ext_vector_type(8))) short;
using short8 = __attribute__((ext_vector_type(8))) short;
using s16x4  = __attribute__((ext_vector_type(4))) short;
using f32x4  = __attribute__((ext_vector_type(4))) float;
using u32x4  = __attribute__((ext_vector_type(4))) unsigned;
using ull    = unsigned long long;

#define T_SEQ 512
#define MFMA(A, B, C) __builtin_amdgcn_mfma_f32_16x16x32_bf16((A), (B), (C), 0, 0, 0)

static constexpr float NL2E  = -1.44269504f;   // -log2(e)
static constexpr float N2L2E = -2.88539008f;   // -2*log2(e)

// Truncation split: hi = bf16-truncate(v), lo = bf16-truncate(v - hi) (residual exact).
__device__ __forceinline__ void split8_tr(f32x4 a, f32x4 b, bf16x8& hi, bf16x8& lo) {
    u32x4 ua = __builtin_bit_cast(u32x4, a);
    u32x4 ub = __builtin_bit_cast(u32x4, b);
    u32x4 m  = {0xffff0000u, 0xffff0000u, 0xffff0000u, 0xffff0000u};
    f32x4 ra = a - __builtin_bit_cast(f32x4, ua & m);
    f32x4 rb = b - __builtin_bit_cast(f32x4, ub & m);
    short8 sa  = __builtin_bit_cast(short8, a);
    short8 sb  = __builtin_bit_cast(short8, b);
    short8 sra = __builtin_bit_cast(short8, ra);
    short8 srb = __builtin_bit_cast(short8, rb);
    hi = __builtin_shufflevector(sa, sb, 1, 3, 5, 7, 9, 11, 13, 15);
    lo = __builtin_shufflevector(sra, srb, 1, 3, 5, 7, 9, 11, 13, 15);
}

__device__ __forceinline__ void split4_tr(f32x4 a, s16x4& hi, s16x4& lo) {
    u32x4 ua = __builtin_bit_cast(u32x4, a);
    u32x4 m  = {0xffff0000u, 0xffff0000u, 0xffff0000u, 0xffff0000u};
    f32x4 ra = a - __builtin_bit_cast(f32x4, ua & m);
    short8 sa  = __builtin_bit_cast(short8, a);
    short8 sra = __builtin_bit_cast(short8, ra);
    hi = __builtin_shufflevector(sa, sa, 1, 3, 5, 7);
    lo = __builtin_shufflevector(sra, sra, 1, 3, 5, 7);
}

// Gates for this wave's 4 hidden units. aR/aZ are state+input merged pre-acts;
// n-gate keeps input side (iN) and state side (sN) separate. Level-major 4-wide.
__device__ __forceinline__ void gate4(f32x4 aR, f32x4 aZ, f32x4 iN, f32x4 sN,
                                      float (&hf)[4]) {
    float er[4], ez[4];
    #pragma unroll
    for (int j = 0; j < 4; ++j) er[j] = __builtin_amdgcn_exp2f(aR[j] * NL2E);
    #pragma unroll
    for (int j = 0; j < 4; ++j) ez[j] = __builtin_amdgcn_exp2f(aZ[j] * NL2E);
    float gr[4], gz[4];
    #pragma unroll
    for (int j = 0; j < 4; ++j) gr[j] = __builtin_amdgcn_rcpf(1.f + er[j]);
    #pragma unroll
    for (int j = 0; j < 4; ++j) gz[j] = __builtin_amdgcn_rcpf(1.f + ez[j]);
    float en[4];
    #pragma unroll
    for (int j = 0; j < 4; ++j) {
        float u = fmaf(gr[j], sN[j], iN[j]);
        en[j] = __builtin_amdgcn_exp2f(fminf(u * N2L2E, 126.f));
    }
    float qn[4];
    #pragma unroll
    for (int j = 0; j < 4; ++j) qn[j] = __builtin_amdgcn_rcpf(1.f + en[j]);
    #pragma unroll
    for (int j = 0; j < 4; ++j) {
        float nn = fmaf(en[j] * qn[j], -2.f, 1.f);
        hf[j] = fmaf(gz[j], hf[j] - nn, nn);
    }
}

// Block = 256 threads = 4 waves = (layer L, row-half m). Wave (L,m) owns tiles
// {m, 2+m, 4+m} (r,z,n for hidden units 16m+4q+j) and publishes its 4 h/lane to
// LDS; half0's outputs are frag elements 0..3, half1's are 4..7 at the SAME
// lane, so a full state B-frag is one contiguous 16B ds_read per lane.
// Frag map: batch = b0+(lane&15), q = lane>>4; elems 0..3 = units 4q+j,
// 4..7 = 16+4q+j (same map A and B). D: col=lane&15, row=4q+reg (m89).
//
// SESSION NOTE (R9-R17): this is the measured optimum (292us). The per-step
// interval (~1650cyc) is jointly issue+latency bound; raw-barrier swap,
// conflict-free exchange, register pins, wave specialization, in-wave G=2,
// K-blocked register recurrence, 2 groups/SIMD, and dep-level flattening all
// measured null or regressed. T=512 serial x 256 groups == CU count leaves no
// spare parallelism axis at this decomposition.
__global__ __launch_bounds__(256, 1)
void gru2_quad(const float* __restrict__ x,
               const float* __restrict__ W_ih0, const float* __restrict__ W_hh0,
               const float* __restrict__ b_ih0, const float* __restrict__ b_hh0,
               const float* __restrict__ W_ih1, const float* __restrict__ W_hh1,
               const float* __restrict__ b_ih1, const float* __restrict__ b_hh1,
               const float* __restrict__ W_proj, const float* __restrict__ b_proj,
               float* __restrict__ out)
{
    const int tid  = threadIdx.x;
    const int wid  = tid >> 6;
    const int L    = wid >> 1;        // 0: layer0, 1: layer1
    const int m    = wid & 1;         // row half
    const int lane = tid & 63;
    const int r16  = lane & 15;
    const int q    = lane >> 4;
    const int b0   = blockIdx.x * 16;

    // publications: [layer][parity][lane][half], hi and lo bf16 halves (8 KB)
    __shared__ ull pubH[2][2][64][2];
    __shared__ ull pubL[2][2][64][2];

    const float* Wx = L ? W_ih1 : W_ih0;
    const float* Wh = L ? W_hh1 : W_hh0;
    const float* bx = L ? b_ih1 : b_ih0;
    const float* bh = L ? b_hh1 : b_hh0;

    // weight fragments for tiles {m, 2+m, 4+m}; g: 0=r, 1=z, 2=n
    bf16x8 WxH[3], WxL[3], WhH[3], WhL[3];
    f32x4 bxf[3], bhf[3];
    #pragma unroll
    for (int g = 0; g < 3; ++g) {
        const int tile = 2 * g + m;
        const float* p1 = Wx + (16 * tile + r16) * 32 + 4 * q;
        split8_tr(*(const f32x4*)p1, *(const f32x4*)(p1 + 16), WxH[g], WxL[g]);
        const float* p2 = Wh + (16 * tile + r16) * 32 + 4 * q;
        split8_tr(*(const f32x4*)p2, *(const f32x4*)(p2 + 16), WhH[g], WhL[g]);
        bxf[g] = *(const f32x4*)(bx + 16 * tile + 4 * q);
        bhf[g] = *(const f32x4*)(bh + 16 * tile + 4 * q);
    }

    float hf[4] = {0.f, 0.f, 0.f, 0.f};
    bf16x8 inh = {}, inl = {};
    const float* xp = x + (size_t)(b0 + r16) * (T_SEQ * 32) + 4 * q;
    f32x4 xA = {}, xB = {};

    if (L == 0) {
        xA = *(const f32x4*)(xp);
        xB = *(const f32x4*)(xp + 16);
        // prologue: h0[0] from x[0], state = 0 (state accs = b_hh frags)
        split8_tr(xA, xB, inh, inl);
        xA = *(const f32x4*)(xp + 32);       // prefetch x[1]
        xB = *(const f32x4*)(xp + 48);
        f32x4 iR = MFMA(WxH[0], inh, bxf[0]);
        f32x4 iZ = MFMA(WxH[1], inh, bxf[1]);
        f32x4 iN = MFMA(WxH[2], inh, bxf[2]);
        iR = MFMA(WxH[0], inl, iR); iZ = MFMA(WxH[1], inl, iZ); iN = MFMA(WxH[2], inl, iN);
        iR = MFMA(WxL[0], inh, iR); iZ = MFMA(WxL[1], inh, iZ); iN = MFMA(WxL[2], inh, iN);
        gate4(iR + bhf[0], iZ + bhf[1], iN, bhf[2], hf);
        s16x4 hi4, lo4;
        split4_tr(f32x4{hf[0], hf[1], hf[2], hf[3]}, hi4, lo4);
        pubH[0][0][lane][m] = __builtin_bit_cast(ull, hi4);
        pubL[0][0][lane][m] = __builtin_bit_cast(ull, lo4);
    } else {
        // zero h1's initial state buffer (read at t=1 as pub1[1])
        if (m == 0) { pubH[1][1][lane][0] = 0; pubH[1][1][lane][1] = 0; }
        else        { pubL[1][1][lane][0] = 0; pubL[1][1][lane][1] = 0; }
    }

    // ---- main loop: wave (0,m) -> h0[t] half, wave (1,m) -> h1[t-1] half ----
    #pragma unroll 1
    for (int t = 1; t < T_SEQ; ++t) {
        __syncthreads();                 // iter t-1 publications visible
        const int pPrev = (t - 1) & 1;
        const int pCur  = t & 1;
        bf16x8 Sh, Sl;
        if (L == 0) {
            Sh = __builtin_bit_cast(bf16x8, *(const u32x4*)&pubH[0][pPrev][lane][0]);
            Sl = __builtin_bit_cast(bf16x8, *(const u32x4*)&pubL[0][pPrev][lane][0]);
            split8_tr(xA, xB, inh, inl); // x[t] (register) under the ds_read wait
            const float* nx = xp + (size_t)((t + 1 < T_SEQ) ? t + 1 : t) * 32;
            xA = *(const f32x4*)(nx);    // prefetch x[t+1]
            xB = *(const f32x4*)(nx + 16);
        } else {
            inh = __builtin_bit_cast(bf16x8, *(const u32x4*)&pubH[0][pPrev][lane][0]);
            inl = __builtin_bit_cast(bf16x8, *(const u32x4*)&pubL[0][pPrev][lane][0]);
            Sh  = __builtin_bit_cast(bf16x8, *(const u32x4*)&pubH[1][pCur][lane][0]);
            Sl  = __builtin_bit_cast(bf16x8, *(const u32x4*)&pubL[1][pCur][lane][0]);
        }

        // 18 MFMAs: input-side chains first (L0: register inputs cover the
        // state ds_read latency), then state-side chains. 6 independent accs.
        f32x4 iR = MFMA(WxH[0], inh, bxf[0]);
        f32x4 iZ = MFMA(WxH[1], inh, bxf[1]);
        f32x4 iN = MFMA(WxH[2], inh, bxf[2]);
        iR = MFMA(WxH[0], inl, iR); iZ = MFMA(WxH[1], inl, iZ); iN = MFMA(WxH[2], inl, iN);
        iR = MFMA(WxL[0], inh, iR); iZ = MFMA(WxL[1], inh, iZ); iN = MFMA(WxL[2], inh, iN);
        f32x4 sR = MFMA(WhH[0], Sh, bhf[0]);
        f32x4 sZ = MFMA(WhH[1], Sh, bhf[1]);
        f32x4 sN = MFMA(WhH[2], Sh, bhf[2]);
        sR = MFMA(WhH[0], Sl, sR); sZ = MFMA(WhH[1], Sl, sZ); sN = MFMA(WhH[2], Sl, sN);
        sR = MFMA(WhL[0], Sh, sR); sZ = MFMA(WhL[1], Sh, sZ); sN = MFMA(WhL[2], Sh, sN);

        gate4(sR + iR, sZ + iZ, iN, sN, hf);

        s16x4 hi4, lo4;
        split4_tr(f32x4{hf[0], hf[1], hf[2], hf[3]}, hi4, lo4);
        const int pW = (L == 0) ? pCur : pPrev;   // L0 writes h0[t], L1 writes h1[t-1]
        pubH[L][pW][lane][m] = __builtin_bit_cast(ull, hi4);
        pubL[L][pW][lane][m] = __builtin_bit_cast(ull, lo4);
    }

    __syncthreads();                     // h0[511] (pub0[1]), h1[510] (pub1[0]) visible
    if (L == 1) {
        // final step: h1[511] from h0[511] and h1[510]
        bf16x8 i2h = __builtin_bit_cast(bf16x8, *(const u32x4*)&pubH[0][1][lane][0]);
        bf16x8 i2l = __builtin_bit_cast(bf16x8, *(const u32x4*)&pubL[0][1][lane][0]);
        bf16x8 Sh  = __builtin_bit_cast(bf16x8, *(const u32x4*)&pubH[1][0][lane][0]);
        bf16x8 Sl  = __builtin_bit_cast(bf16x8, *(const u32x4*)&pubL[1][0][lane][0]);
        f32x4 iR = MFMA(WxH[0], i2h, bxf[0]);
        f32x4 iZ = MFMA(WxH[1], i2h, bxf[1]);
        f32x4 iN = MFMA(WxH[2], i2h, bxf[2]);
        iR = MFMA(WxH[0], i2l, iR); iZ = MFMA(WxH[1], i2l, iZ); iN = MFMA(WxH[2], i2l, iN);
        iR = MFMA(WxL[0], i2h, iR); iZ = MFMA(WxL[1], i2h, iZ); iN = MFMA(WxL[2], i2h, iN);
        f32x4 sR = MFMA(WhH[0], Sh, bhf[0]);
        f32x4 sZ = MFMA(WhH[1], Sh, bhf[1]);
        f32x4 sN = MFMA(WhH[2], Sh, bhf[2]);
        sR = MFMA(WhH[0], Sl, sR); sZ = MFMA(WhH[1], Sl, sZ); sN = MFMA(WhH[2], Sl, sN);
        sR = MFMA(WhL[0], Sh, sR); sZ = MFMA(WhL[1], Sh, sZ); sN = MFMA(WhL[2], Sh, sN);
        gate4(sR + iR, sZ + iZ, iN, sN, hf);
        s16x4 hi4, lo4;
        split4_tr(f32x4{hf[0], hf[1], hf[2], hf[3]}, hi4, lo4);
        pubH[1][1][lane][m] = __builtin_bit_cast(ull, hi4);   // h1[511]
        pubL[1][1][lane][m] = __builtin_bit_cast(ull, lo4);
    }
    __syncthreads();

    if (wid == 2) {
        // projection: out[b][o] = b_proj[o] + sum_u W_proj[o][u] * h1[u]
        bf16x8 Hh = __builtin_bit_cast(bf16x8, *(const u32x4*)&pubH[1][1][lane][0]);
        bf16x8 Hl = __builtin_bit_cast(bf16x8, *(const u32x4*)&pubL[1][1][lane][0]);
        const float* pp = W_proj + r16 * 32 + 4 * q;
        bf16x8 Wph, Wpl;
        split8_tr(*(const f32x4*)pp, *(const f32x4*)(pp + 16), Wph, Wpl);
        f32x4 accp = *(const f32x4*)(b_proj + 4 * q);   // elem reg -> output 4q+reg
        accp = MFMA(Wph, Hh, accp);
        accp = MFMA(Wph, Hl, accp);
        accp = MFMA(Wpl, Hh, accp);
        #pragma unroll
        for (int rg = 0; rg < 4; ++rg)
            out[(b0 + r16) * 16 + 4 * q + rg] = accp[rg];
    }
}

extern "C" void kernel_launch(void* const* d_in, const int* in_sizes, int n_in,
                              void* d_out, int out_size, void* d_ws, size_t ws_size,
                              hipStream_t stream) {
    const float* x      = (const float*)d_in[0];
    const float* W_ih0  = (const float*)d_in[1];
    const float* W_hh0  = (const float*)d_in[2];
    const float* b_ih0  = (const float*)d_in[3];
    const float* b_hh0  = (const float*)d_in[4];
    const float* W_ih1  = (const float*)d_in[5];
    const float* W_hh1  = (const float*)d_in[6];
    const float* b_ih1  = (const float*)d_in[7];
    const float* b_hh1  = (const float*)d_in[8];
    const float* W_proj = (const float*)d_in[9];
    const float* b_proj = (const float*)d_in[10];
    float* out = (float*)d_out;

    const int nb   = in_sizes[0] / (T_SEQ * 32);   // 4096 batch elements
    const int grid = nb / 16;                      // 16 batches per 4-wave block

    hipLaunchKernelGGL(gru2_quad, dim3(grid), dim3(256), 0, stream,
                       x, W_ih0, W_hh0, b_ih0, b_hh0,
                       W_ih1, W_hh1, b_ih1, b_hh1, W_proj, b_proj, out);
}